// Round 4
// baseline (265.248 us; speedup 1.0000x reference)
//
#include <hip/hip_runtime.h>
#include <hip/hip_bf16.h>

// Problem constants (BoundaryPredictor2): B=8, L=1500, D=1024, H=8, HD=128, S=300
// fp32 in/out; bf16 internally for MFMA.
// Key algebraic restructure: scores[b,h,t] = hn[t,:] . qk[h,:] with
// qk[h,:] = sum_d q[h,d] * Wk[h*128+d,:]  -- eliminates the K GEMM entirely.
#define BPK_B 8
#define BPK_L 1500
#define BPK_D 1024
#define BPK_H 8
#define BPK_S 300
#define BPK_EPS 1e-5f
#define BPK_M (BPK_B * BPK_L)      // 12000 token rows
#define BPK_MPAD 12288             // 96 * 128 (8-divisible m-tile count for swizzle)
#define BPK_MS (BPK_B * BPK_S)     // 2400 pooled rows
#define BPK_MSPAD 3072             // 24 * 128

typedef __hip_bfloat16 bf16;
typedef __bf16 bf16x8 __attribute__((ext_vector_type(8)));
typedef float v4f __attribute__((ext_vector_type(4)));

static __device__ __forceinline__ float bf_lo(unsigned u) {
    return __uint_as_float((u & 0xffffu) << 16);
}
static __device__ __forceinline__ float bf_hi(unsigned u) {
    return __uint_as_float((u >> 16) << 16);
}
static __device__ __forceinline__ void bpk_store(float v, float* p) { *p = v; }
static __device__ __forceinline__ void bpk_store(float v, bf16* p) { *p = __float2bfloat16(v); }

// async global->LDS, 16B per lane, lds dest = wave-uniform base + lane*16
#define BPK_GL2LDS(gsrc, ldst)                                                 \
    __builtin_amdgcn_global_load_lds(                                          \
        (const __attribute__((address_space(1))) void*)(gsrc),                 \
        (__attribute__((address_space(3))) void*)(ldst), 16, 0, 0)

// ---------------------------------------------------------------------------
// Kernel 0: fp32 -> bf16 for Wv, Wo (Wk stays fp32; only used via qk).
// ---------------------------------------------------------------------------
__global__ __launch_bounds__(256) void bpk_conv2_kernel(
    const float* __restrict__ s0, const float* __restrict__ s1,
    bf16* __restrict__ d0, bf16* __restrict__ d1) {
    const float* s = blockIdx.y == 0 ? s0 : s1;
    bf16* d = blockIdx.y == 0 ? d0 : d1;
    int i = (blockIdx.x * 256 + threadIdx.x) * 4;
    float4 v = *(const float4*)(s + i);
    bf16* p = d + i;
    p[0] = __float2bfloat16(v.x);
    p[1] = __float2bfloat16(v.y);
    p[2] = __float2bfloat16(v.z);
    p[3] = __float2bfloat16(v.w);
}

// ---------------------------------------------------------------------------
// Kernel 0b: qk[h][k] = sum_{d<128} lq[h*128+d] * Wk[(h*128+d)*1024 + k], fp32.
// 8192 outputs; thread per output; loads coalesced across k.
// ---------------------------------------------------------------------------
__global__ __launch_bounds__(256) void bpk_qk_kernel(const float* __restrict__ lq,
                                                     const float* __restrict__ Wk,
                                                     float* __restrict__ qk) {
    int o = blockIdx.x * 256 + threadIdx.x;     // 0..8191
    int h = o >> 10, k = o & 1023;
    const float* wr = Wk + (size_t)(h * 128) * BPK_D + k;
    const float* qr = lq + h * 128;
    float s = 0.f;
    #pragma unroll 8
    for (int d = 0; d < 128; d++)
        s += qr[d] * wr[(size_t)d * BPK_D];
    qk[o] = s;
}

// ---------------------------------------------------------------------------
// Kernel 1: parallel segment scan. One block per batch.
// ---------------------------------------------------------------------------
__global__ __launch_bounds__(256) void bpk_seg_kernel(
    const float* __restrict__ boundaries, const float* __restrict__ lengths,
    int* __restrict__ seg_start, int* __restrict__ seg_cnt) {
    int b = blockIdx.x;
    int tid = threadIdx.x;
    __shared__ unsigned char flags[1536];
    __shared__ int st_sh[BPK_S + 2];
    __shared__ int wsumi[4];
    int alen = (int)(lengths[b] * (float)BPK_L);   // trunc == .astype(int32)
    const float* bd = boundaries + (size_t)b * BPK_L;
    for (int t = tid; t < 1536; t += 256)
        flags[t] = (t < BPK_L && bd[t] >= 0.5f) ? 1 : 0;
    for (int s = tid; s < BPK_S + 2; s += 256) st_sh[s] = BPK_L;
    __syncthreads();
    int base = tid * 6;
    int lsum = 0;
    #pragma unroll
    for (int j = 0; j < 6; j++) lsum += flags[base + j];
    int lane = tid & 63, wid = tid >> 6;
    int scan = lsum;
    #pragma unroll
    for (int off = 1; off < 64; off <<= 1) {
        int u = __shfl_up(scan, off);
        if (lane >= off) scan += u;
    }
    if (lane == 63) wsumi[wid] = scan;
    __syncthreads();
    int wbase = 0;
    for (int w = 0; w < wid; w++) wbase += wsumi[w];
    int run = wbase + scan - lsum;
    #pragma unroll
    for (int j = 0; j < 6; j++) {
        int t = base + j;
        if (t < BPK_L) {
            int sid = run;
            if ((t == 0 || flags[t - 1]) && sid <= BPK_S) st_sh[sid] = t;
            if (flags[t]) run++;
        }
    }
    __syncthreads();
    for (int s = tid; s < BPK_S; s += 256) {
        int st = st_sh[s];
        int e = min(st_sh[s + 1], alen);
        int s0 = min(st, alen);
        seg_start[b * BPK_S + s] = st;
        seg_cnt[b * BPK_S + s] = max(0, e - s0);
    }
}

// ---------------------------------------------------------------------------
// Kernel 2: LayerNorm (biased variance), fp32 in -> bf16 out. 1 block/row.
// ---------------------------------------------------------------------------
__global__ __launch_bounds__(256) void bpk_ln_kernel(const float* __restrict__ x,
                                                     const float* __restrict__ gamma,
                                                     const float* __restrict__ beta,
                                                     bf16* __restrict__ y) {
    int row = blockIdx.x;
    int tid = threadIdx.x;
    const float* xr = x + (size_t)row * BPK_D;
    float4 f = *(const float4*)(xr + tid * 4);
    float s = f.x + f.y + f.z + f.w;
    float sq = f.x * f.x + f.y * f.y + f.z * f.z + f.w * f.w;
    #pragma unroll
    for (int off = 32; off > 0; off >>= 1) {
        s += __shfl_down(s, off);
        sq += __shfl_down(sq, off);
    }
    __shared__ float ls[4], lsq[4];
    int wid = tid >> 6, lane = tid & 63;
    if (lane == 0) { ls[wid] = s; lsq[wid] = sq; }
    __syncthreads();
    s = ls[0] + ls[1] + ls[2] + ls[3];
    sq = lsq[0] + lsq[1] + lsq[2] + lsq[3];
    float mu = s * (1.0f / BPK_D);
    float var = sq * (1.0f / BPK_D) - mu * mu;
    float rs = rsqrtf(var + BPK_EPS);
    float4 g = *(const float4*)(gamma + tid * 4);
    float4 bb = *(const float4*)(beta + tid * 4);
    bf16* yr = y + (size_t)row * BPK_D + tid * 4;
    yr[0] = __float2bfloat16((f.x - mu) * rs * g.x + bb.x);
    yr[1] = __float2bfloat16((f.y - mu) * rs * g.y + bb.y);
    yr[2] = __float2bfloat16((f.z - mu) * rs * g.z + bb.z);
    yr[3] = __float2bfloat16((f.w - mu) * rs * g.w + bb.w);
}

// ---------------------------------------------------------------------------
// Kernel 3: GEMM O[m,n] = sum_k A[m,k] * W[n,k]. 128x128 tile, BK=32,
// global_load_lds width=16 staging. Flat 1D grid = (mtiles*8) blocks with
// XCD-aware swizzle: dispatch round-robins blocks over 8 XCDs, so map
// flat -> (mt = xcd + 8*(slot>>3), nt = slot&7): all 8 n-blocks of one
// m-tile land consecutively on ONE XCD -> A-tile fetched once per XCD L2.
// (Round 3 counters: FETCH 193.6 MB vs 29 MB ideal = 8x A over-fetch.)
// ---------------------------------------------------------------------------
template <typename OT>
__global__ __launch_bounds__(256) void bpk_gemm_bt_kernel(
    const bf16* __restrict__ A, const bf16* __restrict__ W,
    OT* __restrict__ O, int M) {
    const int flat = blockIdx.x;
    const int xcd = flat & 7, slot = flat >> 3;
    const int mt = xcd + 8 * (slot >> 3);
    const int nt = slot & 7;
    const int n0 = nt * 128;
    const int m0 = mt * 128;
    __shared__ bf16 As[128][32];
    __shared__ bf16 Bs[128][32];
    const int tid = threadIdx.x;
    const int lane = tid & 63, wid = tid >> 6;
    const int wm = (wid & 1) * 64, wn = (wid >> 1) * 64;
    const int lm = lane & 15, quad = lane >> 4;

    const int c0 = wid * 2;
    const int rA = c0 * 16 + (lane >> 2);
    const int colc = (lane & 3) * 8;

    v4f acc[4][4];
    #pragma unroll
    for (int i = 0; i < 4; i++)
        #pragma unroll
        for (int j = 0; j < 4; j++)
            acc[i][j] = (v4f){0.f, 0.f, 0.f, 0.f};

    for (int k0 = 0; k0 < BPK_D; k0 += 32) {
        const bf16* pa = &A[(size_t)(m0 + rA) * BPK_D + k0 + colc];
        const bf16* pw = &W[(size_t)(n0 + rA) * BPK_D + k0 + colc];
        BPK_GL2LDS(pa, &As[c0 * 16][0]);
        BPK_GL2LDS(pa + (size_t)16 * BPK_D, &As[(c0 + 1) * 16][0]);
        BPK_GL2LDS(pw, &Bs[c0 * 16][0]);
        BPK_GL2LDS(pw + (size_t)16 * BPK_D, &Bs[(c0 + 1) * 16][0]);
        __syncthreads();
        bf16x8 af[4], bfr[4];
        #pragma unroll
        for (int i = 0; i < 4; i++)
            af[i] = *(const bf16x8*)&As[wm + i * 16 + lm][quad * 8];
        #pragma unroll
        for (int j = 0; j < 4; j++)
            bfr[j] = *(const bf16x8*)&Bs[wn + j * 16 + lm][quad * 8];
        #pragma unroll
        for (int i = 0; i < 4; i++)
            #pragma unroll
            for (int j = 0; j < 4; j++)
                acc[i][j] = __builtin_amdgcn_mfma_f32_16x16x32_bf16(af[i], bfr[j], acc[i][j], 0, 0, 0);
        __syncthreads();
    }

    // C/D layout: col = lane&15, row = quad*4 + reg  [verified m89/m91]
    #pragma unroll
    for (int i = 0; i < 4; i++) {
        int mbase = m0 + wm + i * 16 + quad * 4;
        #pragma unroll
        for (int j = 0; j < 4; j++) {
            int col = n0 + wn + j * 16 + lm;
            #pragma unroll
            for (int r = 0; r < 4; r++) {
                int m = mbase + r;
                if (m < M) bpk_store(acc[i][j][r], &O[(size_t)m * BPK_D + col]);
            }
        }
    }
}

// ---------------------------------------------------------------------------
// Kernel 4: scores[b,h,t] = (hn[t,:] . qk[h,:]) * 128^-0.5. One wave/token;
// lane = (h = lane>>3, slice p = lane&7 covering k in [p*128, p*128+128)).
// hn row addresses repeat across the 8 h-groups -> coalescer dedups lines.
// ---------------------------------------------------------------------------
__global__ __launch_bounds__(64) void bpk_score_kernel(const bf16* __restrict__ hn,
                                                       const float* __restrict__ qk,
                                                       float* __restrict__ scores) {
    int tok = blockIdx.x;               // = b*L + t
    int b = tok / BPK_L, t = tok - b * BPK_L;
    int lane = threadIdx.x;
    int h = lane >> 3, p = lane & 7;
    const bf16* hr = hn + (size_t)tok * BPK_D + p * 128;
    const float* qr = qk + (size_t)h * BPK_D + p * 128;
    float s = 0.f;
    #pragma unroll
    for (int i = 0; i < 16; i++) {
        uint4 hv = *(const uint4*)(hr + i * 8);
        float4 q0 = *(const float4*)(qr + i * 8);
        float4 q1 = *(const float4*)(qr + i * 8 + 4);
        s += bf_lo(hv.x) * q0.x + bf_hi(hv.x) * q0.y
           + bf_lo(hv.y) * q0.z + bf_hi(hv.y) * q0.w
           + bf_lo(hv.z) * q1.x + bf_hi(hv.z) * q1.y
           + bf_lo(hv.w) * q1.z + bf_hi(hv.w) * q1.w;
    }
    s += __shfl_xor(s, 1);
    s += __shfl_xor(s, 2);
    s += __shfl_xor(s, 4);
    if (p == 0)
        scores[((size_t)b * BPK_H + h) * BPK_L + t] = s * 0.088388347648318447f;
}

// ---------------------------------------------------------------------------
// Kernel 5: per-(b,s) softmax over contiguous segment tokens + weighted V
// pooling. Empty segments -> zeros.
// ---------------------------------------------------------------------------
__global__ __launch_bounds__(256) void bpk_pool_kernel(const float* __restrict__ scores,
                                                       const bf16* __restrict__ V,
                                                       const int* __restrict__ seg_start,
                                                       const int* __restrict__ seg_cnt,
                                                       bf16* __restrict__ pooled) {
    int bs = blockIdx.x;                // = b*S + s
    int b = bs / BPK_S;
    int d0 = threadIdx.x * 4;
    int h = d0 >> 7;
    float a0 = 0.f, a1 = 0.f, a2 = 0.f, a3 = 0.f;
    int cnt = seg_cnt[bs];
    if (cnt > 0) {
        int st = seg_start[bs];
        const float* sc = scores + ((size_t)b * BPK_H + h) * BPK_L + st;
        float m = -1e30f;
        for (int i = 0; i < cnt; i++) m = fmaxf(m, sc[i]);
        float l = 0.f;
        for (int i = 0; i < cnt; i++) l += __expf(sc[i] - m);
        float inv = 1.0f / l;
        const bf16* vp = V + ((size_t)(b * BPK_L + st)) * BPK_D + d0;
        for (int i = 0; i < cnt; i++) {
            float w = __expf(sc[i] - m) * inv;
            uint2 raw = *(const uint2*)(vp + (size_t)i * BPK_D);
            a0 += w * bf_lo(raw.x);
            a1 += w * bf_hi(raw.x);
            a2 += w * bf_lo(raw.y);
            a3 += w * bf_hi(raw.y);
        }
    }
    bf16* pr = pooled + (size_t)bs * BPK_D + d0;
    pr[0] = __float2bfloat16(a0);
    pr[1] = __float2bfloat16(a1);
    pr[2] = __float2bfloat16(a2);
    pr[3] = __float2bfloat16(a3);
}

// ---------------------------------------------------------------------------
extern "C" void kernel_launch(void* const* d_in, const int* in_sizes, int n_in,
                              void* d_out, int out_size, void* d_ws, size_t ws_size,
                              hipStream_t stream) {
    const float* hidden     = (const float*)d_in[0];
    const float* boundaries = (const float*)d_in[1];
    const float* lengths    = (const float*)d_in[2];
    const float* lq         = (const float*)d_in[3];
    const float* Wk         = (const float*)d_in[4];
    const float* Wv         = (const float*)d_in[5];
    const float* Wo         = (const float*)d_in[6];
    const float* gamma      = (const float*)d_in[7];
    const float* beta       = (const float*)d_in[8];
    float* out              = (float*)d_out;

    char* ws = (char*)d_ws;
    size_t off = 0;
    auto carve = [&](size_t bytes) -> char* {
        char* p = ws + off;
        off += (bytes + 255) & ~(size_t)255;
        return p;
    };
    bf16* hn       = (bf16*)carve((size_t)BPK_MPAD * BPK_D * sizeof(bf16));
    bf16* vb       = (bf16*)carve((size_t)BPK_MPAD * BPK_D * sizeof(bf16));
    bf16* wvb      = (bf16*)carve((size_t)BPK_D * BPK_D * sizeof(bf16));
    bf16* wob      = (bf16*)carve((size_t)BPK_D * BPK_D * sizeof(bf16));
    float* qk      = (float*)carve((size_t)BPK_H * BPK_D * sizeof(float));
    float* scores  = (float*)carve((size_t)BPK_B * BPK_H * BPK_L * sizeof(float));
    bf16* pooled   = (bf16*)carve((size_t)BPK_MSPAD * BPK_D * sizeof(bf16));
    int* seg_start = (int*)carve((size_t)BPK_B * BPK_S * sizeof(int));
    int* seg_cnt   = (int*)carve((size_t)BPK_B * BPK_S * sizeof(int));

    const int wgrid = (BPK_D * BPK_D) / (256 * 4);   // 1024 blocks per matrix
    bpk_conv2_kernel<<<dim3(wgrid, 2), dim3(256), 0, stream>>>(Wv, Wo, wvb, wob);
    bpk_qk_kernel<<<dim3(32), dim3(256), 0, stream>>>(lq, Wk, qk);
    bpk_seg_kernel<<<dim3(BPK_B), dim3(256), 0, stream>>>(boundaries, lengths, seg_start, seg_cnt);
    bpk_ln_kernel<<<dim3(BPK_M), dim3(256), 0, stream>>>(hidden, gamma, beta, hn);
    bpk_gemm_bt_kernel<bf16><<<dim3((BPK_MPAD / 128) * 8), dim3(256), 0, stream>>>(hn, wvb, vb, BPK_M);
    bpk_score_kernel<<<dim3(BPK_M), dim3(64), 0, stream>>>(hn, qk, scores);
    bpk_pool_kernel<<<dim3(BPK_MS), dim3(256), 0, stream>>>(scores, vb, seg_start, seg_cnt, pooled);
    bpk_gemm_bt_kernel<float><<<dim3((BPK_MSPAD / 128) * 8), dim3(256), 0, stream>>>(pooled, wob, out, BPK_MS);
}

// Round 5
// 219.170 us; speedup vs baseline: 1.2102x; 1.2102x over previous
//
#include <hip/hip_runtime.h>
#include <hip/hip_bf16.h>

// Problem constants (BoundaryPredictor2): B=8, L=1500, D=1024, H=8, HD=128, S=300
// fp32 in/out; bf16 internally for MFMA.
// Algebraic restructure: scores[b,h,t] = hn[t,:] . qk[h,:] with
//   qk[h,:] = sum_d q[h,d] * Wk[h*128+d,:]
// and the score contraction is FUSED into the V-GEMM as 8 extra weight rows
// (n-tile 8 of an extended 1152-row weight matrix) -- round 4's standalone
// GEMV was L1-tag-bound (64 lines/instr) at 67 us.
#define BPK_B 8
#define BPK_L 1500
#define BPK_D 1024
#define BPK_H 8
#define BPK_S 300
#define BPK_EPS 1e-5f
#define BPK_M (BPK_B * BPK_L)      // 12000 token rows
#define BPK_MPAD 12288             // 96 * 128
#define BPK_MS (BPK_B * BPK_S)     // 2400 pooled rows
#define BPK_MSPAD 3072             // 24 * 128
#define BPK_NEXT 1152              // extended weight rows: 1024 Wv + 8 qk + 120 pad

typedef __hip_bfloat16 bf16;
typedef __bf16 bf16x8 __attribute__((ext_vector_type(8)));
typedef float v4f __attribute__((ext_vector_type(4)));

static __device__ __forceinline__ float bf_lo(unsigned u) {
    return __uint_as_float((u & 0xffffu) << 16);
}
static __device__ __forceinline__ float bf_hi(unsigned u) {
    return __uint_as_float((u >> 16) << 16);
}
static __device__ __forceinline__ void bpk_store(float v, float* p) { *p = v; }
static __device__ __forceinline__ void bpk_store(float v, bf16* p) { *p = __float2bfloat16(v); }

// async global->LDS, 16B per lane, lds dest = wave-uniform base + lane*16
#define BPK_GL2LDS(gsrc, ldst)                                                 \
    __builtin_amdgcn_global_load_lds(                                          \
        (const __attribute__((address_space(1))) void*)(gsrc),                 \
        (__attribute__((address_space(3))) void*)(ldst), 16, 0, 0)

// ---------------------------------------------------------------------------
// Kernel 0: fp32 -> bf16 for Wv (into wext rows 0..1023) and Wo (into wob).
// ---------------------------------------------------------------------------
__global__ __launch_bounds__(256) void bpk_conv2_kernel(
    const float* __restrict__ s0, const float* __restrict__ s1,
    bf16* __restrict__ d0, bf16* __restrict__ d1) {
    const float* s = blockIdx.y == 0 ? s0 : s1;
    bf16* d = blockIdx.y == 0 ? d0 : d1;
    int i = (blockIdx.x * 256 + threadIdx.x) * 4;
    float4 v = *(const float4*)(s + i);
    bf16* p = d + i;
    p[0] = __float2bfloat16(v.x);
    p[1] = __float2bfloat16(v.y);
    p[2] = __float2bfloat16(v.z);
    p[3] = __float2bfloat16(v.w);
}

// ---------------------------------------------------------------------------
// Kernel 0b: qk[h][k] = sum_{d<128} lq[h*128+d] * Wk[(h*128+d)*1024+k], bf16,
// written into wext rows 1024..1031. Blocks >= 32 zero pad rows 1032..1151.
// ---------------------------------------------------------------------------
__global__ __launch_bounds__(256) void bpk_qk_kernel(const float* __restrict__ lq,
                                                     const float* __restrict__ Wk,
                                                     bf16* __restrict__ wext) {
    int blk = blockIdx.x;
    if (blk < 32) {
        int o = blk * 256 + threadIdx.x;        // 0..8191
        int h = o >> 10, k = o & 1023;
        const float* wr = Wk + (size_t)(h * 128) * BPK_D + k;
        const float* qr = lq + h * 128;
        float s = 0.f;
        #pragma unroll 8
        for (int d = 0; d < 128; d++)
            s += qr[d] * wr[(size_t)d * BPK_D];
        wext[(size_t)(1024 + h) * BPK_D + k] = __float2bfloat16(s);
    } else {
        // zero rows 1032..1151: 120*1024 bf16 = 15360 uint4
        int o = (blk - 32) * 256 + threadIdx.x; // 0..15359
        uint4* p = (uint4*)(wext + (size_t)1032 * BPK_D);
        p[o] = (uint4){0, 0, 0, 0};
    }
}

// ---------------------------------------------------------------------------
// Kernel 1: parallel segment scan. One block per batch.
// ---------------------------------------------------------------------------
__global__ __launch_bounds__(256) void bpk_seg_kernel(
    const float* __restrict__ boundaries, const float* __restrict__ lengths,
    int* __restrict__ seg_start, int* __restrict__ seg_cnt) {
    int b = blockIdx.x;
    int tid = threadIdx.x;
    __shared__ unsigned char flags[1536];
    __shared__ int st_sh[BPK_S + 2];
    __shared__ int wsumi[4];
    int alen = (int)(lengths[b] * (float)BPK_L);   // trunc == .astype(int32)
    const float* bd = boundaries + (size_t)b * BPK_L;
    for (int t = tid; t < 1536; t += 256)
        flags[t] = (t < BPK_L && bd[t] >= 0.5f) ? 1 : 0;
    for (int s = tid; s < BPK_S + 2; s += 256) st_sh[s] = BPK_L;
    __syncthreads();
    int base = tid * 6;
    int lsum = 0;
    #pragma unroll
    for (int j = 0; j < 6; j++) lsum += flags[base + j];
    int lane = tid & 63, wid = tid >> 6;
    int scan = lsum;
    #pragma unroll
    for (int off = 1; off < 64; off <<= 1) {
        int u = __shfl_up(scan, off);
        if (lane >= off) scan += u;
    }
    if (lane == 63) wsumi[wid] = scan;
    __syncthreads();
    int wbase = 0;
    for (int w = 0; w < wid; w++) wbase += wsumi[w];
    int run = wbase + scan - lsum;
    #pragma unroll
    for (int j = 0; j < 6; j++) {
        int t = base + j;
        if (t < BPK_L) {
            int sid = run;
            if ((t == 0 || flags[t - 1]) && sid <= BPK_S) st_sh[sid] = t;
            if (flags[t]) run++;
        }
    }
    __syncthreads();
    for (int s = tid; s < BPK_S; s += 256) {
        int st = st_sh[s];
        int e = min(st_sh[s + 1], alen);
        int s0 = min(st, alen);
        seg_start[b * BPK_S + s] = st;
        seg_cnt[b * BPK_S + s] = max(0, e - s0);
    }
}

// ---------------------------------------------------------------------------
// Kernel 2: LayerNorm (biased variance), fp32 in -> bf16 out. 1 block/row.
// ---------------------------------------------------------------------------
__global__ __launch_bounds__(256) void bpk_ln_kernel(const float* __restrict__ x,
                                                     const float* __restrict__ gamma,
                                                     const float* __restrict__ beta,
                                                     bf16* __restrict__ y) {
    int row = blockIdx.x;
    int tid = threadIdx.x;
    const float* xr = x + (size_t)row * BPK_D;
    float4 f = *(const float4*)(xr + tid * 4);
    float s = f.x + f.y + f.z + f.w;
    float sq = f.x * f.x + f.y * f.y + f.z * f.z + f.w * f.w;
    #pragma unroll
    for (int off = 32; off > 0; off >>= 1) {
        s += __shfl_down(s, off);
        sq += __shfl_down(sq, off);
    }
    __shared__ float ls[4], lsq[4];
    int wid = tid >> 6, lane = tid & 63;
    if (lane == 0) { ls[wid] = s; lsq[wid] = sq; }
    __syncthreads();
    s = ls[0] + ls[1] + ls[2] + ls[3];
    sq = lsq[0] + lsq[1] + lsq[2] + lsq[3];
    float mu = s * (1.0f / BPK_D);
    float var = sq * (1.0f / BPK_D) - mu * mu;
    float rs = rsqrtf(var + BPK_EPS);
    float4 g = *(const float4*)(gamma + tid * 4);
    float4 bb = *(const float4*)(beta + tid * 4);
    bf16* yr = y + (size_t)row * BPK_D + tid * 4;
    yr[0] = __float2bfloat16((f.x - mu) * rs * g.x + bb.x);
    yr[1] = __float2bfloat16((f.y - mu) * rs * g.y + bb.y);
    yr[2] = __float2bfloat16((f.z - mu) * rs * g.z + bb.z);
    yr[3] = __float2bfloat16((f.w - mu) * rs * g.w + bb.w);
}

// ---------------------------------------------------------------------------
// Kernel 3: GEMM O[m,n] = sum_k A[m,k] * W[n,k]. 128x128 tile, BK=32,
// global_load_lds width=16 staging, XCD-aware flat swizzle (NT n-tiles per
// m-tile placed consecutively on one XCD). If nt==8 (V-GEMM's extended tile),
// epilogue routes cols 1024..1031 to the scores buffer with 128^-0.5 scale.
// ---------------------------------------------------------------------------
template <typename OT>
__global__ __launch_bounds__(256) void bpk_gemm_bt_kernel(
    const bf16* __restrict__ A, const bf16* __restrict__ W,
    OT* __restrict__ O, float* __restrict__ scores, int M, int NT) {
    const int flat = blockIdx.x;
    const int xcd = flat & 7, slot = flat >> 3;
    const int mt = xcd + 8 * (slot / NT);
    const int nt = slot % NT;
    const int n0 = nt * 128;
    const int m0 = mt * 128;
    __shared__ bf16 As[128][32];
    __shared__ bf16 Bs[128][32];
    const int tid = threadIdx.x;
    const int lane = tid & 63, wid = tid >> 6;
    const int wm = (wid & 1) * 64, wn = (wid >> 1) * 64;
    const int lm = lane & 15, quad = lane >> 4;

    const int c0 = wid * 2;
    const int rA = c0 * 16 + (lane >> 2);
    const int colc = (lane & 3) * 8;

    v4f acc[4][4];
    #pragma unroll
    for (int i = 0; i < 4; i++)
        #pragma unroll
        for (int j = 0; j < 4; j++)
            acc[i][j] = (v4f){0.f, 0.f, 0.f, 0.f};

    for (int k0 = 0; k0 < BPK_D; k0 += 32) {
        const bf16* pa = &A[(size_t)(m0 + rA) * BPK_D + k0 + colc];
        const bf16* pw = &W[(size_t)(n0 + rA) * BPK_D + k0 + colc];
        BPK_GL2LDS(pa, &As[c0 * 16][0]);
        BPK_GL2LDS(pa + (size_t)16 * BPK_D, &As[(c0 + 1) * 16][0]);
        BPK_GL2LDS(pw, &Bs[c0 * 16][0]);
        BPK_GL2LDS(pw + (size_t)16 * BPK_D, &Bs[(c0 + 1) * 16][0]);
        __syncthreads();
        bf16x8 af[4], bfr[4];
        #pragma unroll
        for (int i = 0; i < 4; i++)
            af[i] = *(const bf16x8*)&As[wm + i * 16 + lm][quad * 8];
        #pragma unroll
        for (int j = 0; j < 4; j++)
            bfr[j] = *(const bf16x8*)&Bs[wn + j * 16 + lm][quad * 8];
        #pragma unroll
        for (int i = 0; i < 4; i++)
            #pragma unroll
            for (int j = 0; j < 4; j++)
                acc[i][j] = __builtin_amdgcn_mfma_f32_16x16x32_bf16(af[i], bfr[j], acc[i][j], 0, 0, 0);
        __syncthreads();
    }

    // C/D layout: col = lane&15, row = quad*4 + reg  [verified m89/m91]
    if (nt != 8) {
        #pragma unroll
        for (int i = 0; i < 4; i++) {
            int mbase = m0 + wm + i * 16 + quad * 4;
            #pragma unroll
            for (int j = 0; j < 4; j++) {
                int col = n0 + wn + j * 16 + lm;
                #pragma unroll
                for (int r = 0; r < 4; r++) {
                    int m = mbase + r;
                    if (m < M) bpk_store(acc[i][j][r], &O[(size_t)m * BPK_D + col]);
                }
            }
        }
    } else if (wn == 0 && lm < 8) {
        // score tile: cols 1024..1031 -> scores[(b*8+h)*1500 + t], scaled
        const float kSc = 0.088388347648318447f;   // 128^-0.5
        int h = lm;
        #pragma unroll
        for (int i = 0; i < 4; i++) {
            int mbase = m0 + wm + i * 16 + quad * 4;
            #pragma unroll
            for (int r = 0; r < 4; r++) {
                int m = mbase + r;
                if (m < M) {
                    int b = m / BPK_L, t = m - b * BPK_L;
                    scores[((size_t)b * BPK_H + h) * BPK_L + t] = acc[i][0][r] * kSc;
                }
            }
        }
    }
}

// ---------------------------------------------------------------------------
// Kernel 5: per-(b,s) softmax over contiguous segment tokens + weighted V
// pooling. Empty segments -> zeros.
// ---------------------------------------------------------------------------
__global__ __launch_bounds__(256) void bpk_pool_kernel(const float* __restrict__ scores,
                                                       const bf16* __restrict__ V,
                                                       const int* __restrict__ seg_start,
                                                       const int* __restrict__ seg_cnt,
                                                       bf16* __restrict__ pooled) {
    int bs = blockIdx.x;                // = b*S + s
    int b = bs / BPK_S;
    int d0 = threadIdx.x * 4;
    int h = d0 >> 7;
    float a0 = 0.f, a1 = 0.f, a2 = 0.f, a3 = 0.f;
    int cnt = seg_cnt[bs];
    if (cnt > 0) {
        int st = seg_start[bs];
        const float* sc = scores + ((size_t)b * BPK_H + h) * BPK_L + st;
        float m = -1e30f;
        for (int i = 0; i < cnt; i++) m = fmaxf(m, sc[i]);
        float l = 0.f;
        for (int i = 0; i < cnt; i++) l += __expf(sc[i] - m);
        float inv = 1.0f / l;
        const bf16* vp = V + ((size_t)(b * BPK_L + st)) * BPK_D + d0;
        for (int i = 0; i < cnt; i++) {
            float w = __expf(sc[i] - m) * inv;
            uint2 raw = *(const uint2*)(vp + (size_t)i * BPK_D);
            a0 += w * bf_lo(raw.x);
            a1 += w * bf_hi(raw.x);
            a2 += w * bf_lo(raw.y);
            a3 += w * bf_hi(raw.y);
        }
    }
    bf16* pr = pooled + (size_t)bs * BPK_D + d0;
    pr[0] = __float2bfloat16(a0);
    pr[1] = __float2bfloat16(a1);
    pr[2] = __float2bfloat16(a2);
    pr[3] = __float2bfloat16(a3);
}

// ---------------------------------------------------------------------------
extern "C" void kernel_launch(void* const* d_in, const int* in_sizes, int n_in,
                              void* d_out, int out_size, void* d_ws, size_t ws_size,
                              hipStream_t stream) {
    const float* hidden     = (const float*)d_in[0];
    const float* boundaries = (const float*)d_in[1];
    const float* lengths    = (const float*)d_in[2];
    const float* lq         = (const float*)d_in[3];
    const float* Wk         = (const float*)d_in[4];
    const float* Wv         = (const float*)d_in[5];
    const float* Wo         = (const float*)d_in[6];
    const float* gamma      = (const float*)d_in[7];
    const float* beta       = (const float*)d_in[8];
    float* out              = (float*)d_out;

    char* ws = (char*)d_ws;
    size_t off = 0;
    auto carve = [&](size_t bytes) -> char* {
        char* p = ws + off;
        off += (bytes + 255) & ~(size_t)255;
        return p;
    };
    bf16* hn       = (bf16*)carve((size_t)BPK_MPAD * BPK_D * sizeof(bf16));
    bf16* vb       = (bf16*)carve((size_t)BPK_MPAD * BPK_D * sizeof(bf16));
    bf16* wext     = (bf16*)carve((size_t)BPK_NEXT * BPK_D * sizeof(bf16));
    bf16* wob      = (bf16*)carve((size_t)BPK_D * BPK_D * sizeof(bf16));
    float* scores  = (float*)carve((size_t)BPK_B * BPK_H * BPK_L * sizeof(float));
    bf16* pooled   = (bf16*)carve((size_t)BPK_MSPAD * BPK_D * sizeof(bf16));
    int* seg_start = (int*)carve((size_t)BPK_B * BPK_S * sizeof(int));
    int* seg_cnt   = (int*)carve((size_t)BPK_B * BPK_S * sizeof(int));

    const int wgrid = (BPK_D * BPK_D) / (256 * 4);   // 1024 blocks per matrix
    bpk_conv2_kernel<<<dim3(wgrid, 2), dim3(256), 0, stream>>>(Wv, Wo, wext, wob);
    bpk_qk_kernel<<<dim3(92), dim3(256), 0, stream>>>(lq, Wk, wext);
    bpk_seg_kernel<<<dim3(BPK_B), dim3(256), 0, stream>>>(boundaries, lengths, seg_start, seg_cnt);
    bpk_ln_kernel<<<dim3(BPK_M), dim3(256), 0, stream>>>(hidden, gamma, beta, hn);
    // V-GEMM + fused scores: 96 m-tiles x 9 n-tiles (tile 8 = qk rows)
    bpk_gemm_bt_kernel<bf16><<<dim3((BPK_MPAD / 128) * 9), dim3(256), 0, stream>>>(
        hn, wext, vb, scores, BPK_M, 9);
    bpk_pool_kernel<<<dim3(BPK_MS), dim3(256), 0, stream>>>(scores, vb, seg_start, seg_cnt, pooled);
    bpk_gemm_bt_kernel<float><<<dim3((BPK_MSPAD / 128) * 8), dim3(256), 0, stream>>>(
        pooled, wob, out, nullptr, BPK_MS, 8);
}

// Round 6
// 218.877 us; speedup vs baseline: 1.2119x; 1.0013x over previous
//
#include <hip/hip_runtime.h>
#include <hip/hip_bf16.h>

// BoundaryPredictor2: B=8, L=1500, D=1024, H=8, HD=128, S=300. fp32 in/out.
// Algebraic restructure (round 6): pooling commutes with the V projection:
//   pooled[b,s,h,:] = (sum_t w[b,h,s,t] * hn[b,t,:]) @ Wv_h^T
// so the 25.8-GFLOP V-GEMM (60 us, latency-bound at 864 blocks) is replaced by
// a 0.15-GFLOP weighted pooling of hn (hpool) + 5-GFLOP per-head GEMMs.
// Scores fused into LN (hn row live in registers; qk bf16 table in LDS).
#define BPK_B 8
#define BPK_L 1500
#define BPK_D 1024
#define BPK_H 8
#define BPK_S 300
#define BPK_EPS 1e-5f
#define BPK_M (BPK_B * BPK_L)      // 12000 token rows
#define BPK_MS (BPK_B * BPK_S)     // 2400 pooled rows
#define BPK_MS_TILES 19            // ceil(2400/128)
#define BPK_HP_ROWS 2432           // 19*128 rows per head (hpool padding)
#define BPK_PO_PAD 3072            // 24*128 rows (O-GEMM A padding)

typedef __hip_bfloat16 bf16;
typedef __bf16 bf16x8 __attribute__((ext_vector_type(8)));
typedef float v4f __attribute__((ext_vector_type(4)));

static __device__ __forceinline__ float bf_lo(unsigned u) {
    return __uint_as_float((u & 0xffffu) << 16);
}
static __device__ __forceinline__ float bf_hi(unsigned u) {
    return __uint_as_float((u >> 16) << 16);
}
static __device__ __forceinline__ void bpk_store(float v, float* p) { *p = v; }
static __device__ __forceinline__ void bpk_store(float v, bf16* p) { *p = __float2bfloat16(v); }
static __device__ __forceinline__ uint2 pack4bf(float a, float b, float c, float d) {
    union { bf16 h[4]; uint2 u; } pk;
    pk.h[0] = __float2bfloat16(a); pk.h[1] = __float2bfloat16(b);
    pk.h[2] = __float2bfloat16(c); pk.h[3] = __float2bfloat16(d);
    return pk.u;
}

// async global->LDS, 16B per lane, lds dest = wave-uniform base + lane*16
#define BPK_GL2LDS(gsrc, ldst)                                                 \
    __builtin_amdgcn_global_load_lds(                                          \
        (const __attribute__((address_space(1))) void*)(gsrc),                 \
        (__attribute__((address_space(3))) void*)(ldst), 16, 0, 0)

// ---------------------------------------------------------------------------
// Kernel 1: fused prep. blocks 0..2047: Wv/Wo fp32->bf16; 2048..2079: qk
// precompute (qk[h,:] = sum_d lq[h*128+d]*Wk[h*128+d,:], bf16); 2080..2087:
// per-batch parallel segment scan.
// ---------------------------------------------------------------------------
__global__ __launch_bounds__(256) void bpk_prep_kernel(
    const float* __restrict__ Wv, const float* __restrict__ Wo,
    const float* __restrict__ lq, const float* __restrict__ Wk,
    const float* __restrict__ boundaries, const float* __restrict__ lengths,
    bf16* __restrict__ wvb, bf16* __restrict__ wob, bf16* __restrict__ qkb,
    int* __restrict__ seg_start, int* __restrict__ seg_cnt) {
    __shared__ unsigned char flags[1536];
    __shared__ int st_sh[BPK_S + 2];
    __shared__ int wsumi[4];
    int blk = blockIdx.x;
    int tid = threadIdx.x;
    if (blk < 2048) {
        const float* s = blk < 1024 ? Wv : Wo;
        bf16* d = blk < 1024 ? wvb : wob;
        int i = ((blk & 1023) * 256 + tid) * 4;
        float4 v = *(const float4*)(s + i);
        *(uint2*)(d + i) = pack4bf(v.x, v.y, v.z, v.w);
        return;
    }
    if (blk < 2080) {
        int o = (blk - 2048) * 256 + tid;       // 0..8191
        int h = o >> 10, k = o & 1023;
        const float* wr = Wk + (size_t)(h * 128) * BPK_D + k;
        const float* qr = lq + h * 128;
        float s = 0.f;
        #pragma unroll 8
        for (int d = 0; d < 128; d++)
            s += qr[d] * wr[(size_t)d * BPK_D];
        qkb[o] = __float2bfloat16(s);
        return;
    }
    // segment scan, b = blk - 2080
    int b = blk - 2080;
    int alen = (int)(lengths[b] * (float)BPK_L);   // trunc == .astype(int32)
    const float* bd = boundaries + (size_t)b * BPK_L;
    for (int t = tid; t < 1536; t += 256)
        flags[t] = (t < BPK_L && bd[t] >= 0.5f) ? 1 : 0;
    for (int s = tid; s < BPK_S + 2; s += 256) st_sh[s] = BPK_L;
    __syncthreads();
    int base = tid * 6;
    int lsum = 0;
    #pragma unroll
    for (int j = 0; j < 6; j++) lsum += flags[base + j];
    int lane = tid & 63, wid = tid >> 6;
    int scan = lsum;
    #pragma unroll
    for (int off = 1; off < 64; off <<= 1) {
        int u = __shfl_up(scan, off);
        if (lane >= off) scan += u;
    }
    if (lane == 63) wsumi[wid] = scan;
    __syncthreads();
    int wbase = 0;
    for (int w = 0; w < wid; w++) wbase += wsumi[w];
    int run = wbase + scan - lsum;
    #pragma unroll
    for (int j = 0; j < 6; j++) {
        int t = base + j;
        if (t < BPK_L) {
            int sid = run;
            if ((t == 0 || flags[t - 1]) && sid <= BPK_S) st_sh[sid] = t;
            if (flags[t]) run++;
        }
    }
    __syncthreads();
    for (int s = tid; s < BPK_S; s += 256) {
        int st = st_sh[s];
        int e = min(st_sh[s + 1], alen);
        int s0 = min(st, alen);
        seg_start[b * BPK_S + s] = st;
        seg_cnt[b * BPK_S + s] = max(0, e - s0);
    }
}

// ---------------------------------------------------------------------------
// Kernel 2: LayerNorm + fused scores. Grid-stride over rows; qk table (bf16,
// 16 KB) loaded to LDS once per block. Per row: mean/var block-reduce ->
// normalized fp32 values -> hn (bf16) + 8 per-head dot products with qk ->
// block-reduce -> scores (fp32).
// ---------------------------------------------------------------------------
__global__ __launch_bounds__(256) void bpk_ln_score_kernel(
    const float* __restrict__ x, const float* __restrict__ gamma,
    const float* __restrict__ beta, const bf16* __restrict__ qkb,
    bf16* __restrict__ hn, float* __restrict__ scores) {
    __shared__ bf16 qks[BPK_H * BPK_D];          // 16 KB
    __shared__ float ls[4], lsq[4], red[4][8];
    int tid = threadIdx.x;
    int lane = tid & 63, wid = tid >> 6;
    for (int i = tid; i < (BPK_H * BPK_D) / 8; i += 256)
        ((uint4*)qks)[i] = ((const uint4*)qkb)[i];
    float4 g = *(const float4*)(gamma + tid * 4);
    float4 bb = *(const float4*)(beta + tid * 4);
    __syncthreads();

    for (int row = blockIdx.x; row < BPK_M; row += gridDim.x) {
        float4 f = *(const float4*)(x + (size_t)row * BPK_D + tid * 4);
        float s = f.x + f.y + f.z + f.w;
        float sq = f.x * f.x + f.y * f.y + f.z * f.z + f.w * f.w;
        #pragma unroll
        for (int off = 32; off > 0; off >>= 1) {
            s += __shfl_down(s, off);
            sq += __shfl_down(sq, off);
        }
        if (lane == 0) { ls[wid] = s; lsq[wid] = sq; }
        __syncthreads();
        s = ls[0] + ls[1] + ls[2] + ls[3];
        sq = lsq[0] + lsq[1] + lsq[2] + lsq[3];
        float mu = s * (1.0f / BPK_D);
        float var = sq * (1.0f / BPK_D) - mu * mu;
        float rs = rsqrtf(var + BPK_EPS);
        float h0 = (f.x - mu) * rs * g.x + bb.x;
        float h1 = (f.y - mu) * rs * g.y + bb.y;
        float h2 = (f.z - mu) * rs * g.z + bb.z;
        float h3 = (f.w - mu) * rs * g.w + bb.w;
        *(uint2*)(hn + (size_t)row * BPK_D + tid * 4) = pack4bf(h0, h1, h2, h3);
        // per-head score partials vs LDS qk (fp32 hn x bf16 qk)
        float p[8];
        #pragma unroll
        for (int h = 0; h < 8; h++) {
            uint2 qv = *(const uint2*)(qks + h * BPK_D + tid * 4);
            p[h] = h0 * bf_lo(qv.x) + h1 * bf_hi(qv.x)
                 + h2 * bf_lo(qv.y) + h3 * bf_hi(qv.y);
        }
        #pragma unroll
        for (int h = 0; h < 8; h++)
            #pragma unroll
            for (int off = 32; off > 0; off >>= 1)
                p[h] += __shfl_down(p[h], off);
        if (lane == 0)
            #pragma unroll
            for (int h = 0; h < 8; h++) red[wid][h] = p[h];
        __syncthreads();
        if (tid < 8) {
            float sc = red[0][tid] + red[1][tid] + red[2][tid] + red[3][tid];
            int b = row / BPK_L, t = row - b * BPK_L;
            scores[((size_t)b * BPK_H + tid) * BPK_L + t] = sc * 0.088388347648318447f;
        }
        __syncthreads();   // protect ls/red before next row
    }
}

// ---------------------------------------------------------------------------
// Kernel 3: per-(b,s) softmax + weighted pooling of hn into per-head hpool:
//   hpool[h][bs][k] = sum_t softmax_w[b,h,s,t] * hn[b,t,k]
// Block 256: thread owns 4 k-dims for ALL 8 heads (32 accumulators).
// Weights computed chunk-wise into LDS (128 tokens/chunk). Empty seg -> 0.
// ---------------------------------------------------------------------------
__global__ __launch_bounds__(256) void bpk_pool_kernel(
    const float* __restrict__ scores, const bf16* __restrict__ hn,
    const int* __restrict__ seg_start, const int* __restrict__ seg_cnt,
    bf16* __restrict__ hpool) {
    int bs = blockIdx.x;                // = b*S + s
    int b = bs / BPK_S;
    int tid = threadIdx.x;
    __shared__ float minv[8][2];
    __shared__ float wls[8][128];
    int cnt = seg_cnt[bs], st = seg_start[bs];
    float acc[8][4];
    #pragma unroll
    for (int h = 0; h < 8; h++)
        #pragma unroll
        for (int j = 0; j < 4; j++) acc[h][j] = 0.f;
    if (cnt > 0) {
        if (tid < 8) {
            const float* sc = scores + ((size_t)(b * 8 + tid)) * BPK_L + st;
            float m = -1e30f;
            for (int i = 0; i < cnt; i++) m = fmaxf(m, sc[i]);
            float l = 0.f;
            for (int i = 0; i < cnt; i++) l += __expf(sc[i] - m);
            minv[tid][0] = m;
            minv[tid][1] = 1.0f / l;
        }
        __syncthreads();
        for (int cb = 0; cb < cnt; cb += 128) {
            int cc = min(128, cnt - cb);
            int hh = tid >> 5, i0 = (tid & 31) * 4;
            #pragma unroll
            for (int j = 0; j < 4; j++) {
                int i = i0 + j;
                if (i < cc)
                    wls[hh][i] = __expf(scores[((size_t)(b * 8 + hh)) * BPK_L + st + cb + i]
                                        - minv[hh][0]) * minv[hh][1];
            }
            __syncthreads();
            const bf16* hp = hn + (size_t)(b * BPK_L + st + cb) * BPK_D + tid * 4;
            for (int i = 0; i < cc; i++) {
                uint2 raw = *(const uint2*)(hp + (size_t)i * BPK_D);
                float x0 = bf_lo(raw.x), x1 = bf_hi(raw.x);
                float x2 = bf_lo(raw.y), x3 = bf_hi(raw.y);
                #pragma unroll
                for (int h = 0; h < 8; h++) {
                    float w = wls[h][i];
                    acc[h][0] += w * x0; acc[h][1] += w * x1;
                    acc[h][2] += w * x2; acc[h][3] += w * x3;
                }
            }
            __syncthreads();
        }
    }
    #pragma unroll
    for (int h = 0; h < 8; h++)
        *(uint2*)(hpool + ((size_t)h * BPK_HP_ROWS + bs) * BPK_D + tid * 4) =
            pack4bf(acc[h][0], acc[h][1], acc[h][2], acc[h][3]);
}

// ---------------------------------------------------------------------------
// Kernel 4: per-head GEMM. pooled[bs, h*128+d] = sum_k hpool[h][bs,k]*Wv[h*128+d,k]
// Grid (19 m-tiles, 8 heads); 128x128 tile, BK=32, global_load_lds staging.
// ---------------------------------------------------------------------------
__global__ __launch_bounds__(256) void bpk_headgemm_kernel(
    const bf16* __restrict__ hpool, const bf16* __restrict__ wvb,
    bf16* __restrict__ pooled) {
    const int mt = blockIdx.x, h = blockIdx.y;
    const int m0 = mt * 128;
    const bf16* A = hpool + (size_t)h * BPK_HP_ROWS * BPK_D;
    const bf16* W = wvb + (size_t)(h * 128) * BPK_D;
    __shared__ bf16 As[128][32];
    __shared__ bf16 Bs[128][32];
    const int tid = threadIdx.x;
    const int lane = tid & 63, wid = tid >> 6;
    const int wm = (wid & 1) * 64, wn = (wid >> 1) * 64;
    const int lm = lane & 15, quad = lane >> 4;
    const int c0 = wid * 2;
    const int rA = c0 * 16 + (lane >> 2);
    const int colc = (lane & 3) * 8;

    v4f acc[4][4];
    #pragma unroll
    for (int i = 0; i < 4; i++)
        #pragma unroll
        for (int j = 0; j < 4; j++) acc[i][j] = (v4f){0.f, 0.f, 0.f, 0.f};

    for (int k0 = 0; k0 < BPK_D; k0 += 32) {
        const bf16* pa = &A[(size_t)(m0 + rA) * BPK_D + k0 + colc];
        const bf16* pw = &W[(size_t)rA * BPK_D + k0 + colc];
        BPK_GL2LDS(pa, &As[c0 * 16][0]);
        BPK_GL2LDS(pa + (size_t)16 * BPK_D, &As[(c0 + 1) * 16][0]);
        BPK_GL2LDS(pw, &Bs[c0 * 16][0]);
        BPK_GL2LDS(pw + (size_t)16 * BPK_D, &Bs[(c0 + 1) * 16][0]);
        __syncthreads();
        bf16x8 af[4], bfr[4];
        #pragma unroll
        for (int i = 0; i < 4; i++)
            af[i] = *(const bf16x8*)&As[wm + i * 16 + lm][quad * 8];
        #pragma unroll
        for (int j = 0; j < 4; j++)
            bfr[j] = *(const bf16x8*)&Bs[wn + j * 16 + lm][quad * 8];
        #pragma unroll
        for (int i = 0; i < 4; i++)
            #pragma unroll
            for (int j = 0; j < 4; j++)
                acc[i][j] = __builtin_amdgcn_mfma_f32_16x16x32_bf16(af[i], bfr[j], acc[i][j], 0, 0, 0);
        __syncthreads();
    }
    #pragma unroll
    for (int i = 0; i < 4; i++) {
        int mbase = m0 + wm + i * 16 + quad * 4;
        #pragma unroll
        for (int j = 0; j < 4; j++) {
            int col = h * 128 + wn + j * 16 + lm;
            #pragma unroll
            for (int r = 0; r < 4; r++) {
                int m = mbase + r;
                if (m < BPK_MS)
                    pooled[(size_t)m * BPK_D + col] = __float2bfloat16(acc[i][j][r]);
            }
        }
    }
}

// ---------------------------------------------------------------------------
// Kernel 5: O-GEMM out[m,n] = sum_k pooled[m,k]*Wo[n,k]. XCD-swizzled flat
// grid (NT n-tiles consecutive per XCD). fp32 output, guard m<M.
// ---------------------------------------------------------------------------
template <typename OT>
__global__ __launch_bounds__(256) void bpk_gemm_bt_kernel(
    const bf16* __restrict__ A, const bf16* __restrict__ W,
    OT* __restrict__ O, int M, int NT) {
    const int flat = blockIdx.x;
    const int xcd = flat & 7, slot = flat >> 3;
    const int mt = xcd + 8 * (slot / NT);
    const int nt = slot % NT;
    const int n0 = nt * 128;
    const int m0 = mt * 128;
    __shared__ bf16 As[128][32];
    __shared__ bf16 Bs[128][32];
    const int tid = threadIdx.x;
    const int lane = tid & 63, wid = tid >> 6;
    const int wm = (wid & 1) * 64, wn = (wid >> 1) * 64;
    const int lm = lane & 15, quad = lane >> 4;
    const int c0 = wid * 2;
    const int rA = c0 * 16 + (lane >> 2);
    const int colc = (lane & 3) * 8;

    v4f acc[4][4];
    #pragma unroll
    for (int i = 0; i < 4; i++)
        #pragma unroll
        for (int j = 0; j < 4; j++) acc[i][j] = (v4f){0.f, 0.f, 0.f, 0.f};

    for (int k0 = 0; k0 < BPK_D; k0 += 32) {
        const bf16* pa = &A[(size_t)(m0 + rA) * BPK_D + k0 + colc];
        const bf16* pw = &W[(size_t)(n0 + rA) * BPK_D + k0 + colc];
        BPK_GL2LDS(pa, &As[c0 * 16][0]);
        BPK_GL2LDS(pa + (size_t)16 * BPK_D, &As[(c0 + 1) * 16][0]);
        BPK_GL2LDS(pw, &Bs[c0 * 16][0]);
        BPK_GL2LDS(pw + (size_t)16 * BPK_D, &Bs[(c0 + 1) * 16][0]);
        __syncthreads();
        bf16x8 af[4], bfr[4];
        #pragma unroll
        for (int i = 0; i < 4; i++)
            af[i] = *(const bf16x8*)&As[wm + i * 16 + lm][quad * 8];
        #pragma unroll
        for (int j = 0; j < 4; j++)
            bfr[j] = *(const bf16x8*)&Bs[wn + j * 16 + lm][quad * 8];
        #pragma unroll
        for (int i = 0; i < 4; i++)
            #pragma unroll
            for (int j = 0; j < 4; j++)
                acc[i][j] = __builtin_amdgcn_mfma_f32_16x16x32_bf16(af[i], bfr[j], acc[i][j], 0, 0, 0);
        __syncthreads();
    }
    #pragma unroll
    for (int i = 0; i < 4; i++) {
        int mbase = m0 + wm + i * 16 + quad * 4;
        #pragma unroll
        for (int j = 0; j < 4; j++) {
            int col = n0 + wn + j * 16 + lm;
            #pragma unroll
            for (int r = 0; r < 4; r++) {
                int m = mbase + r;
                if (m < M) bpk_store(acc[i][j][r], &O[(size_t)m * BPK_D + col]);
            }
        }
    }
}

// ---------------------------------------------------------------------------
extern "C" void kernel_launch(void* const* d_in, const int* in_sizes, int n_in,
                              void* d_out, int out_size, void* d_ws, size_t ws_size,
                              hipStream_t stream) {
    const float* hidden     = (const float*)d_in[0];
    const float* boundaries = (const float*)d_in[1];
    const float* lengths    = (const float*)d_in[2];
    const float* lq         = (const float*)d_in[3];
    const float* Wk         = (const float*)d_in[4];
    const float* Wv         = (const float*)d_in[5];
    const float* Wo         = (const float*)d_in[6];
    const float* gamma      = (const float*)d_in[7];
    const float* beta       = (const float*)d_in[8];
    float* out              = (float*)d_out;

    char* ws = (char*)d_ws;
    size_t off = 0;
    auto carve = [&](size_t bytes) -> char* {
        char* p = ws + off;
        off += (bytes + 255) & ~(size_t)255;
        return p;
    };
    bf16* hn       = (bf16*)carve((size_t)BPK_M * BPK_D * sizeof(bf16));      // 24.6 MB
    bf16* hpool    = (bf16*)carve((size_t)BPK_H * BPK_HP_ROWS * BPK_D * sizeof(bf16)); // 39.8 MB
    bf16* wvb      = (bf16*)carve((size_t)BPK_D * BPK_D * sizeof(bf16));
    bf16* wob      = (bf16*)carve((size_t)BPK_D * BPK_D * sizeof(bf16));
    bf16* qkb      = (bf16*)carve((size_t)BPK_H * BPK_D * sizeof(bf16));
    float* scores  = (float*)carve((size_t)BPK_B * BPK_H * BPK_L * sizeof(float));
    int* seg_start = (int*)carve((size_t)BPK_B * BPK_S * sizeof(int));
    int* seg_cnt   = (int*)carve((size_t)BPK_B * BPK_S * sizeof(int));
    // pooled (3072x1024 bf16, 6.3 MB) aliases hn -- hn is dead once pool ran.
    bf16* pooled   = hn;

    bpk_prep_kernel<<<dim3(2088), dim3(256), 0, stream>>>(
        Wv, Wo, lq, Wk, boundaries, lengths, wvb, wob, qkb, seg_start, seg_cnt);
    bpk_ln_score_kernel<<<dim3(1024), dim3(256), 0, stream>>>(
        hidden, gamma, beta, qkb, hn, scores);
    bpk_pool_kernel<<<dim3(BPK_MS), dim3(256), 0, stream>>>(
        scores, hn, seg_start, seg_cnt, hpool);
    bpk_headgemm_kernel<<<dim3(BPK_MS_TILES, BPK_H), dim3(256), 0, stream>>>(
        hpool, wvb, pooled);
    bpk_gemm_bt_kernel<float><<<dim3((BPK_PO_PAD / 128) * 8), dim3(256), 0, stream>>>(
        pooled, wob, out, BPK_MS, 8);
}

// Round 7
// 190.419 us; speedup vs baseline: 1.3930x; 1.1495x over previous
//
#include <hip/hip_runtime.h>
#include <hip/hip_bf16.h>

// BoundaryPredictor2: B=8, L=1500, D=1024, H=8, HD=128, S=300. fp32 in/out.
// Structure: prep (weights->bf16, qk=q@Wk, segment scan) -> LN+scores (fused,
// wave-per-row) -> softmax-pool of hn (hpool, per head) -> per-head GEMM
// (hpool @ Wv_h^T) -> O-GEMM. The V-GEMM is algebraically eliminated
// (pooling commutes with the V projection).
#define BPK_B 8
#define BPK_L 1500
#define BPK_D 1024
#define BPK_H 8
#define BPK_S 300
#define BPK_EPS 1e-5f
#define BPK_M (BPK_B * BPK_L)      // 12000 token rows
#define BPK_MS (BPK_B * BPK_S)     // 2400 pooled rows
#define BPK_MS_TILES 19            // ceil(2400/128)
#define BPK_HP_ROWS 2432           // 19*128 rows per head (hpool padding)
#define BPK_PO_PAD 3072            // 24*128 rows (O-GEMM A padding)

typedef __hip_bfloat16 bf16;
typedef __bf16 bf16x8 __attribute__((ext_vector_type(8)));
typedef float v4f __attribute__((ext_vector_type(4)));

static __device__ __forceinline__ float bf_lo(unsigned u) {
    return __uint_as_float((u & 0xffffu) << 16);
}
static __device__ __forceinline__ float bf_hi(unsigned u) {
    return __uint_as_float((u >> 16) << 16);
}
static __device__ __forceinline__ void bpk_store(float v, float* p) { *p = v; }
static __device__ __forceinline__ void bpk_store(float v, bf16* p) { *p = __float2bfloat16(v); }
static __device__ __forceinline__ uint2 pack4bf(float a, float b, float c, float d) {
    union { bf16 h[4]; uint2 u; } pk;
    pk.h[0] = __float2bfloat16(a); pk.h[1] = __float2bfloat16(b);
    pk.h[2] = __float2bfloat16(c); pk.h[3] = __float2bfloat16(d);
    return pk.u;
}

// async global->LDS, 16B per lane, lds dest = wave-uniform base + lane*16
#define BPK_GL2LDS(gsrc, ldst)                                                 \
    __builtin_amdgcn_global_load_lds(                                          \
        (const __attribute__((address_space(1))) void*)(gsrc),                 \
        (__attribute__((address_space(3))) void*)(ldst), 16, 0, 0)

// ---------------------------------------------------------------------------
// Kernel 1: fused prep. blocks 0..2047: Wv/Wo fp32->bf16; 2048..2079: qk
// precompute; 2080..2087: per-batch parallel segment scan.
// ---------------------------------------------------------------------------
__global__ __launch_bounds__(256) void bpk_prep_kernel(
    const float* __restrict__ Wv, const float* __restrict__ Wo,
    const float* __restrict__ lq, const float* __restrict__ Wk,
    const float* __restrict__ boundaries, const float* __restrict__ lengths,
    bf16* __restrict__ wvb, bf16* __restrict__ wob, bf16* __restrict__ qkb,
    int* __restrict__ seg_start, int* __restrict__ seg_cnt) {
    __shared__ unsigned char flags[1536];
    __shared__ int st_sh[BPK_S + 2];
    __shared__ int wsumi[4];
    int blk = blockIdx.x;
    int tid = threadIdx.x;
    if (blk < 2048) {
        const float* s = blk < 1024 ? Wv : Wo;
        bf16* d = blk < 1024 ? wvb : wob;
        int i = ((blk & 1023) * 256 + tid) * 4;
        float4 v = *(const float4*)(s + i);
        *(uint2*)(d + i) = pack4bf(v.x, v.y, v.z, v.w);
        return;
    }
    if (blk < 2080) {
        int o = (blk - 2048) * 256 + tid;       // 0..8191
        int h = o >> 10, k = o & 1023;
        const float* wr = Wk + (size_t)(h * 128) * BPK_D + k;
        const float* qr = lq + h * 128;
        float s = 0.f;
        #pragma unroll 8
        for (int d = 0; d < 128; d++)
            s += qr[d] * wr[(size_t)d * BPK_D];
        qkb[o] = __float2bfloat16(s);
        return;
    }
    // segment scan, b = blk - 2080
    int b = blk - 2080;
    int alen = (int)(lengths[b] * (float)BPK_L);   // trunc == .astype(int32)
    const float* bd = boundaries + (size_t)b * BPK_L;
    for (int t = tid; t < 1536; t += 256)
        flags[t] = (t < BPK_L && bd[t] >= 0.5f) ? 1 : 0;
    for (int s = tid; s < BPK_S + 2; s += 256) st_sh[s] = BPK_L;
    __syncthreads();
    int base = tid * 6;
    int lsum = 0;
    #pragma unroll
    for (int j = 0; j < 6; j++) lsum += flags[base + j];
    int lane = tid & 63, wid = tid >> 6;
    int scan = lsum;
    #pragma unroll
    for (int off = 1; off < 64; off <<= 1) {
        int u = __shfl_up(scan, off);
        if (lane >= off) scan += u;
    }
    if (lane == 63) wsumi[wid] = scan;
    __syncthreads();
    int wbase = 0;
    for (int w = 0; w < wid; w++) wbase += wsumi[w];
    int run = wbase + scan - lsum;
    #pragma unroll
    for (int j = 0; j < 6; j++) {
        int t = base + j;
        if (t < BPK_L) {
            int sid = run;
            if ((t == 0 || flags[t - 1]) && sid <= BPK_S) st_sh[sid] = t;
            if (flags[t]) run++;
        }
    }
    __syncthreads();
    for (int s = tid; s < BPK_S; s += 256) {
        int st = st_sh[s];
        int e = min(st_sh[s + 1], alen);
        int s0 = min(st, alen);
        seg_start[b * BPK_S + s] = st;
        seg_cnt[b * BPK_S + s] = max(0, e - s0);
    }
}

// ---------------------------------------------------------------------------
// Kernel 2: LayerNorm + fused scores, WAVE-PER-ROW (round 6's block-per-row
// was latency-bound at 50 us: 3 syncthreads + 2 LDS round-trips per row).
// Lane l owns dims {l*4 + 256j : j<4} -> fully coalesced fp32 loads and bf16
// stores. Mean/var + 8 head dots reduced via 6-step shfl_xor butterflies --
// no __syncthreads in the row loop. qk (bf16, 16 KB) in LDS; gamma/beta in
// registers.
// ---------------------------------------------------------------------------
__global__ __launch_bounds__(256) void bpk_ln_score_kernel(
    const float* __restrict__ x, const float* __restrict__ gamma,
    const float* __restrict__ beta, const bf16* __restrict__ qkb,
    bf16* __restrict__ hn, float* __restrict__ scores) {
    __shared__ bf16 qks[BPK_H * BPK_D];          // 16 KB
    int tid = threadIdx.x;
    int lane = tid & 63, wid = tid >> 6;
    for (int i = tid; i < (BPK_H * BPK_D) / 8; i += 256)
        ((uint4*)qks)[i] = ((const uint4*)qkb)[i];
    float4 g[4], bb[4];
    #pragma unroll
    for (int j = 0; j < 4; j++) {
        g[j]  = *(const float4*)(gamma + j * 256 + lane * 4);
        bb[j] = *(const float4*)(beta + j * 256 + lane * 4);
    }
    __syncthreads();
    const int nwaves = gridDim.x * 4;
    for (int row = blockIdx.x * 4 + wid; row < BPK_M; row += nwaves) {
        const float* xr = x + (size_t)row * BPK_D;
        float4 f[4];
        float s = 0.f, sq = 0.f;
        #pragma unroll
        for (int j = 0; j < 4; j++) {
            f[j] = *(const float4*)(xr + j * 256 + lane * 4);
            s  += f[j].x + f[j].y + f[j].z + f[j].w;
            sq += f[j].x * f[j].x + f[j].y * f[j].y
                + f[j].z * f[j].z + f[j].w * f[j].w;
        }
        #pragma unroll
        for (int off = 1; off < 64; off <<= 1) {
            s  += __shfl_xor(s, off);
            sq += __shfl_xor(sq, off);
        }
        float mu = s * (1.0f / BPK_D);
        float var = sq * (1.0f / BPK_D) - mu * mu;
        float rs = rsqrtf(var + BPK_EPS);
        float hv[16];
        #pragma unroll
        for (int j = 0; j < 4; j++) {
            hv[j * 4 + 0] = (f[j].x - mu) * rs * g[j].x + bb[j].x;
            hv[j * 4 + 1] = (f[j].y - mu) * rs * g[j].y + bb[j].y;
            hv[j * 4 + 2] = (f[j].z - mu) * rs * g[j].z + bb[j].z;
            hv[j * 4 + 3] = (f[j].w - mu) * rs * g[j].w + bb[j].w;
        }
        bf16* yr = hn + (size_t)row * BPK_D;
        #pragma unroll
        for (int j = 0; j < 4; j++)
            *(uint2*)(yr + j * 256 + lane * 4) =
                pack4bf(hv[j * 4], hv[j * 4 + 1], hv[j * 4 + 2], hv[j * 4 + 3]);
        float p[8];
        #pragma unroll
        for (int h = 0; h < 8; h++) {
            p[h] = 0.f;
            #pragma unroll
            for (int j = 0; j < 4; j++) {
                uint2 qv = *(const uint2*)(qks + h * BPK_D + j * 256 + lane * 4);
                p[h] += hv[j * 4 + 0] * bf_lo(qv.x) + hv[j * 4 + 1] * bf_hi(qv.x)
                      + hv[j * 4 + 2] * bf_lo(qv.y) + hv[j * 4 + 3] * bf_hi(qv.y);
            }
        }
        #pragma unroll
        for (int h = 0; h < 8; h++)
            #pragma unroll
            for (int off = 1; off < 64; off <<= 1)
                p[h] += __shfl_xor(p[h], off);
        if (lane < 8) {
            int b = row / BPK_L, t = row - b * BPK_L;
            scores[((size_t)b * BPK_H + lane) * BPK_L + t] =
                p[lane] * 0.088388347648318447f;
        }
    }
}

// ---------------------------------------------------------------------------
// Kernel 3: per-(b,s) softmax + weighted pooling of hn into per-head hpool.
// Wave 0 computes per-head max/sum with 8 lanes per head (xor-reduce over
// masks 8/16/32) -- round 6's 8-serial-thread scan was a straggler tail for
// long segments. Then chunked weights in LDS + 32-accumulator update.
// ---------------------------------------------------------------------------
__global__ __launch_bounds__(256) void bpk_pool_kernel(
    const float* __restrict__ scores, const bf16* __restrict__ hn,
    const int* __restrict__ seg_start, const int* __restrict__ seg_cnt,
    bf16* __restrict__ hpool) {
    int bs = blockIdx.x;                // = b*S + s
    int b = bs / BPK_S;
    int tid = threadIdx.x;
    int lane = tid & 63, wid = tid >> 6;
    __shared__ float minv[8][2];
    __shared__ float wls[8][128];
    int cnt = seg_cnt[bs], st = seg_start[bs];
    float acc[8][4];
    #pragma unroll
    for (int h = 0; h < 8; h++)
        #pragma unroll
        for (int j = 0; j < 4; j++) acc[h][j] = 0.f;
    if (cnt > 0) {
        if (wid == 0) {
            int h = lane & 7, i0 = lane >> 3;   // 8 lanes per head
            const float* sc = scores + ((size_t)(b * 8 + h)) * BPK_L + st;
            float m = -1e30f;
            for (int i = i0; i < cnt; i += 8) m = fmaxf(m, sc[i]);
            #pragma unroll
            for (int off = 8; off < 64; off <<= 1) m = fmaxf(m, __shfl_xor(m, off));
            float l = 0.f;
            for (int i = i0; i < cnt; i += 8) l += __expf(sc[i] - m);
            #pragma unroll
            for (int off = 8; off < 64; off <<= 1) l += __shfl_xor(l, off);
            if (i0 == 0) { minv[h][0] = m; minv[h][1] = 1.0f / l; }
        }
        __syncthreads();
        for (int cb = 0; cb < cnt; cb += 128) {
            int cc = min(128, cnt - cb);
            int hh = tid >> 5, i0 = (tid & 31) * 4;
            #pragma unroll
            for (int j = 0; j < 4; j++) {
                int i = i0 + j;
                if (i < cc)
                    wls[hh][i] = __expf(scores[((size_t)(b * 8 + hh)) * BPK_L + st + cb + i]
                                        - minv[hh][0]) * minv[hh][1];
            }
            __syncthreads();
            const bf16* hp = hn + (size_t)(b * BPK_L + st + cb) * BPK_D + tid * 4;
            for (int i = 0; i < cc; i++) {
                uint2 raw = *(const uint2*)(hp + (size_t)i * BPK_D);
                float x0 = bf_lo(raw.x), x1 = bf_hi(raw.x);
                float x2 = bf_lo(raw.y), x3 = bf_hi(raw.y);
                #pragma unroll
                for (int h = 0; h < 8; h++) {
                    float w = wls[h][i];
                    acc[h][0] += w * x0; acc[h][1] += w * x1;
                    acc[h][2] += w * x2; acc[h][3] += w * x3;
                }
            }
            __syncthreads();
        }
    }
    #pragma unroll
    for (int h = 0; h < 8; h++)
        *(uint2*)(hpool + ((size_t)h * BPK_HP_ROWS + bs) * BPK_D + tid * 4) =
            pack4bf(acc[h][0], acc[h][1], acc[h][2], acc[h][3]);
}

// ---------------------------------------------------------------------------
// Kernel 4: per-head GEMM. pooled[bs, h*128+d] = sum_k hpool[h][bs,k]*Wv[h*128+d,k]
// Grid (19 m-tiles, 8 heads); 128x128 tile, BK=32, global_load_lds staging.
// ---------------------------------------------------------------------------
__global__ __launch_bounds__(256) void bpk_headgemm_kernel(
    const bf16* __restrict__ hpool, const bf16* __restrict__ wvb,
    bf16* __restrict__ pooled) {
    const int mt = blockIdx.x, h = blockIdx.y;
    const int m0 = mt * 128;
    const bf16* A = hpool + (size_t)h * BPK_HP_ROWS * BPK_D;
    const bf16* W = wvb + (size_t)(h * 128) * BPK_D;
    __shared__ bf16 As[128][32];
    __shared__ bf16 Bs[128][32];
    const int tid = threadIdx.x;
    const int lane = tid & 63, wid = tid >> 6;
    const int wm = (wid & 1) * 64, wn = (wid >> 1) * 64;
    const int lm = lane & 15, quad = lane >> 4;
    const int c0 = wid * 2;
    const int rA = c0 * 16 + (lane >> 2);
    const int colc = (lane & 3) * 8;

    v4f acc[4][4];
    #pragma unroll
    for (int i = 0; i < 4; i++)
        #pragma unroll
        for (int j = 0; j < 4; j++) acc[i][j] = (v4f){0.f, 0.f, 0.f, 0.f};

    for (int k0 = 0; k0 < BPK_D; k0 += 32) {
        const bf16* pa = &A[(size_t)(m0 + rA) * BPK_D + k0 + colc];
        const bf16* pw = &W[(size_t)rA * BPK_D + k0 + colc];
        BPK_GL2LDS(pa, &As[c0 * 16][0]);
        BPK_GL2LDS(pa + (size_t)16 * BPK_D, &As[(c0 + 1) * 16][0]);
        BPK_GL2LDS(pw, &Bs[c0 * 16][0]);
        BPK_GL2LDS(pw + (size_t)16 * BPK_D, &Bs[(c0 + 1) * 16][0]);
        __syncthreads();
        bf16x8 af[4], bfr[4];
        #pragma unroll
        for (int i = 0; i < 4; i++)
            af[i] = *(const bf16x8*)&As[wm + i * 16 + lm][quad * 8];
        #pragma unroll
        for (int j = 0; j < 4; j++)
            bfr[j] = *(const bf16x8*)&Bs[wn + j * 16 + lm][quad * 8];
        #pragma unroll
        for (int i = 0; i < 4; i++)
            #pragma unroll
            for (int j = 0; j < 4; j++)
                acc[i][j] = __builtin_amdgcn_mfma_f32_16x16x32_bf16(af[i], bfr[j], acc[i][j], 0, 0, 0);
        __syncthreads();
    }
    #pragma unroll
    for (int i = 0; i < 4; i++) {
        int mbase = m0 + wm + i * 16 + quad * 4;
        #pragma unroll
        for (int j = 0; j < 4; j++) {
            int col = h * 128 + wn + j * 16 + lm;
            #pragma unroll
            for (int r = 0; r < 4; r++) {
                int m = mbase + r;
                if (m < BPK_MS)
                    pooled[(size_t)m * BPK_D + col] = __float2bfloat16(acc[i][j][r]);
            }
        }
    }
}

// ---------------------------------------------------------------------------
// Kernel 5: O-GEMM out[m,n] = sum_k pooled[m,k]*Wo[n,k]. XCD-swizzled flat
// grid (NT n-tiles consecutive per XCD). fp32 output, guard m<M.
// ---------------------------------------------------------------------------
template <typename OT>
__global__ __launch_bounds__(256) void bpk_gemm_bt_kernel(
    const bf16* __restrict__ A, const bf16* __restrict__ W,
    OT* __restrict__ O, int M, int NT) {
    const int flat = blockIdx.x;
    const int xcd = flat & 7, slot = flat >> 3;
    const int mt = xcd + 8 * (slot / NT);
    const int nt = slot % NT;
    const int n0 = nt * 128;
    const int m0 = mt * 128;
    __shared__ bf16 As[128][32];
    __shared__ bf16 Bs[128][32];
    const int tid = threadIdx.x;
    const int lane = tid & 63, wid = tid >> 6;
    const int wm = (wid & 1) * 64, wn = (wid >> 1) * 64;
    const int lm = lane & 15, quad = lane >> 4;
    const int c0 = wid * 2;
    const int rA = c0 * 16 + (lane >> 2);
    const int colc = (lane & 3) * 8;

    v4f acc[4][4];
    #pragma unroll
    for (int i = 0; i < 4; i++)
        #pragma unroll
        for (int j = 0; j < 4; j++) acc[i][j] = (v4f){0.f, 0.f, 0.f, 0.f};

    for (int k0 = 0; k0 < BPK_D; k0 += 32) {
        const bf16* pa = &A[(size_t)(m0 + rA) * BPK_D + k0 + colc];
        const bf16* pw = &W[(size_t)(n0 + rA) * BPK_D + k0 + colc];
        BPK_GL2LDS(pa, &As[c0 * 16][0]);
        BPK_GL2LDS(pa + (size_t)16 * BPK_D, &As[(c0 + 1) * 16][0]);
        BPK_GL2LDS(pw, &Bs[c0 * 16][0]);
        BPK_GL2LDS(pw + (size_t)16 * BPK_D, &Bs[(c0 + 1) * 16][0]);
        __syncthreads();
        bf16x8 af[4], bfr[4];
        #pragma unroll
        for (int i = 0; i < 4; i++)
            af[i] = *(const bf16x8*)&As[wm + i * 16 + lm][quad * 8];
        #pragma unroll
        for (int j = 0; j < 4; j++)
            bfr[j] = *(const bf16x8*)&Bs[wn + j * 16 + lm][quad * 8];
        #pragma unroll
        for (int i = 0; i < 4; i++)
            #pragma unroll
            for (int j = 0; j < 4; j++)
                acc[i][j] = __builtin_amdgcn_mfma_f32_16x16x32_bf16(af[i], bfr[j], acc[i][j], 0, 0, 0);
        __syncthreads();
    }
    #pragma unroll
    for (int i = 0; i < 4; i++) {
        int mbase = m0 + wm + i * 16 + quad * 4;
        #pragma unroll
        for (int j = 0; j < 4; j++) {
            int col = n0 + wn + j * 16 + lm;
            #pragma unroll
            for (int r = 0; r < 4; r++) {
                int m = mbase + r;
                if (m < M) bpk_store(acc[i][j][r], &O[(size_t)m * BPK_D + col]);
            }
        }
    }
}

// ---------------------------------------------------------------------------
extern "C" void kernel_launch(void* const* d_in, const int* in_sizes, int n_in,
                              void* d_out, int out_size, void* d_ws, size_t ws_size,
                              hipStream_t stream) {
    const float* hidden     = (const float*)d_in[0];
    const float* boundaries = (const float*)d_in[1];
    const float* lengths    = (const float*)d_in[2];
    const float* lq         = (const float*)d_in[3];
    const float* Wk         = (const float*)d_in[4];
    const float* Wv         = (const float*)d_in[5];
    const float* Wo         = (const float*)d_in[6];
    const float* gamma      = (const float*)d_in[7];
    const float* beta       = (const float*)d_in[8];
    float* out              = (float*)d_out;

    char* ws = (char*)d_ws;
    size_t off = 0;
    auto carve = [&](size_t bytes) -> char* {
        char* p = ws + off;
        off += (bytes + 255) & ~(size_t)255;
        return p;
    };
    bf16* hn       = (bf16*)carve((size_t)BPK_M * BPK_D * sizeof(bf16));      // 24.6 MB
    bf16* hpool    = (bf16*)carve((size_t)BPK_H * BPK_HP_ROWS * BPK_D * sizeof(bf16)); // 39.8 MB
    bf16* wvb      = (bf16*)carve((size_t)BPK_D * BPK_D * sizeof(bf16));
    bf16* wob      = (bf16*)carve((size_t)BPK_D * BPK_D * sizeof(bf16));
    bf16* qkb      = (bf16*)carve((size_t)BPK_H * BPK_D * sizeof(bf16));
    float* scores  = (float*)carve((size_t)BPK_B * BPK_H * BPK_L * sizeof(float));
    int* seg_start = (int*)carve((size_t)BPK_B * BPK_S * sizeof(int));
    int* seg_cnt   = (int*)carve((size_t)BPK_B * BPK_S * sizeof(int));
    // pooled (3072x1024 bf16, 6.3 MB) aliases hn -- hn is dead once pool ran.
    bf16* pooled   = hn;

    bpk_prep_kernel<<<dim3(2088), dim3(256), 0, stream>>>(
        Wv, Wo, lq, Wk, boundaries, lengths, wvb, wob, qkb, seg_start, seg_cnt);
    bpk_ln_score_kernel<<<dim3(1024), dim3(256), 0, stream>>>(
        hidden, gamma, beta, qkb, hn, scores);
    bpk_pool_kernel<<<dim3(BPK_MS), dim3(256), 0, stream>>>(
        scores, hn, seg_start, seg_cnt, hpool);
    bpk_headgemm_kernel<<<dim3(BPK_MS_TILES, BPK_H), dim3(256), 0, stream>>>(
        hpool, wvb, pooled);
    bpk_gemm_bt_kernel<float><<<dim3((BPK_PO_PAD / 128) * 8), dim3(256), 0, stream>>>(
        pooled, wob, out, BPK_MS, 8);
}